// Round 1
// baseline (3374.788 us; speedup 1.0000x reference)
//
#include <hip/hip_runtime.h>
#include <math.h>

#define K_NN 20
#define NEG_SLOPE 0.2f

constexpr int NSEG = 8;    // j-range segments per query (parallelism for knn)
constexpr int TJ   = 128;  // point-tile staged in LDS

// ---------------------------------------------------------------------------
// sq[i] = sum_c x[i][c]^2
template<int C>
__global__ __launch_bounds__(256) void sqnorm_kernel(const float* __restrict__ x,
                                                     float* __restrict__ sq, int N) {
    int i = blockIdx.x * 256 + threadIdx.x;
    if (i < N) {
        float s = 0.f;
#pragma unroll
        for (int c = 0; c < C; ++c) { float v = x[i * C + c]; s += v * v; }
        sq[i] = s;
    }
}

// ---------------------------------------------------------------------------
// Fused pairwise-distance + per-segment top-20. One thread per query.
// Block = 256 threads = 256 queries; blockIdx covers (query_tile, segment).
// Point tile staged in LDS; all lanes read the same tile element (broadcast).
template<int C>
__global__ __launch_bounds__(256) void knn_partial_kernel(const float* __restrict__ x,
                                                          const float* __restrict__ sq,
                                                          float* __restrict__ pdist,
                                                          int* __restrict__ pidx, int N) {
    __shared__ float tile[TJ * C];
    __shared__ float tsq[TJ];

    const int qblk = blockIdx.x / NSEG;
    const int seg  = blockIdx.x % NSEG;
    const int q    = qblk * 256 + threadIdx.x;
    const int segLen = N / NSEG;
    const int j0   = seg * segLen;

    float qf[C];
#pragma unroll
    for (int c = 0; c < C; ++c) qf[c] = x[q * C + c];
    const float qsq = sq[q];

    float dl[K_NN]; int il[K_NN];
#pragma unroll
    for (int p = 0; p < K_NN; ++p) { dl[p] = __builtin_inff(); il[p] = 0; }

    for (int t0 = 0; t0 < segLen; t0 += TJ) {
        __syncthreads();
        for (int u = threadIdx.x; u < TJ * C; u += 256)
            tile[u] = x[(j0 + t0) * C + u];
        for (int u = threadIdx.x; u < TJ; u += 256)
            tsq[u] = sq[j0 + t0 + u];
        __syncthreads();

        for (int t = 0; t < TJ; ++t) {
            float dot = 0.f;
#pragma unroll
            for (int c = 0; c < C; ++c) dot += qf[c] * tile[t * C + c];
            float d = qsq - 2.f * dot + tsq[t];
            if (d < dl[K_NN - 1]) {
                dl[K_NN - 1] = d; il[K_NN - 1] = j0 + t0 + t;
                // single bubble pass; strict < keeps earlier (smaller-index) ties first
#pragma unroll
                for (int p = K_NN - 1; p > 0; --p) {
                    if (dl[p] < dl[p - 1]) {
                        float td = dl[p]; dl[p] = dl[p - 1]; dl[p - 1] = td;
                        int   ti = il[p]; il[p] = il[p - 1]; il[p - 1] = ti;
                    }
                }
            }
        }
    }

    const long base = ((long)q * NSEG + seg) * K_NN;
#pragma unroll
    for (int p = 0; p < K_NN; ++p) { pdist[base + p] = dl[p]; pidx[base + p] = il[p]; }
}

// ---------------------------------------------------------------------------
// Merge NSEG sorted partial lists -> final top-20 indices per query.
__global__ __launch_bounds__(256) void knn_merge_kernel(const float* __restrict__ pdist,
                                                        const int* __restrict__ pidx,
                                                        int* __restrict__ knn, int N) {
    int q = blockIdx.x * 256 + threadIdx.x;
    if (q >= N) return;
    float dl[K_NN]; int il[K_NN];
#pragma unroll
    for (int p = 0; p < K_NN; ++p) { dl[p] = __builtin_inff(); il[p] = 0; }

    for (int s = 0; s < NSEG; ++s) {
        const long base = ((long)q * NSEG + s) * K_NN;
        for (int p = 0; p < K_NN; ++p) {
            float d = pdist[base + p];
            if (!(d < dl[K_NN - 1])) break;  // partial list is sorted ascending
            int id = pidx[base + p];
            dl[K_NN - 1] = d; il[K_NN - 1] = id;
#pragma unroll
            for (int u = K_NN - 1; u > 0; --u) {
                if (dl[u] < dl[u - 1]) {
                    float td = dl[u]; dl[u] = dl[u - 1]; dl[u - 1] = td;
                    int   ti = il[u]; il[u] = il[u - 1]; il[u - 1] = ti;
                }
            }
        }
    }
#pragma unroll
    for (int p = 0; p < K_NN; ++p) knn[(long)q * K_NN + p] = il[p];
}

// ---------------------------------------------------------------------------
// A[i][f] = b[f] + sum_c x[i][c]*W[c][f] ;  U[i][f] = sum_c x[i][c]*W[C+c][f]
template<int C, int F>
__global__ __launch_bounds__(256) void proj_kernel(const float* __restrict__ x,
                                                   const float* __restrict__ W,
                                                   const float* __restrict__ b,
                                                   float* __restrict__ A,
                                                   float* __restrict__ U, int N) {
    int gid = blockIdx.x * 256 + threadIdx.x;
    int i = gid / F, f = gid % F;
    if (i >= N) return;
    float a = b[f], u = 0.f;
#pragma unroll
    for (int c = 0; c < C; ++c) {
        float xv = x[i * C + c];
        a += xv * W[c * F + f];
        u += xv * W[(C + c) * F + f];
    }
    A[(long)i * F + f] = a;
    U[(long)i * F + f] = u;
}

// ---------------------------------------------------------------------------
// out[i][f] = max_k leaky_relu(A[i][f] - U[i][f] + U[knn[i][k]][f])
template<int F>
__global__ __launch_bounds__(256) void agg_kernel(const float* __restrict__ A,
                                                  const float* __restrict__ U,
                                                  const int* __restrict__ knn,
                                                  float* __restrict__ out, int N) {
    int gid = blockIdx.x * 256 + threadIdx.x;
    int i = gid / F, f = gid % F;
    if (i >= N) return;
    float a = A[(long)i * F + f] - U[(long)i * F + f];
    float m = -__builtin_inff();
#pragma unroll
    for (int k = 0; k < K_NN; ++k) {
        int j = knn[(long)i * K_NN + k];
        float v = a + U[(long)j * F + f];
        v = fmaxf(v, v * NEG_SLOPE);  // leaky_relu (slope 0.2 > 0)
        m = fmaxf(m, v);
    }
    out[(long)i * F + f] = m;
}

// ---------------------------------------------------------------------------
extern "C" void kernel_launch(void* const* d_in, const int* in_sizes, int n_in,
                              void* d_out, int out_size, void* d_ws, size_t ws_size,
                              hipStream_t stream) {
    const float* x  = (const float*)d_in[0];
    const float* W1 = (const float*)d_in[1];
    const float* b1 = (const float*)d_in[2];
    const float* W2 = (const float*)d_in[3];
    const float* b2 = (const float*)d_in[4];
    const float* W3 = (const float*)d_in[5];
    const float* b3 = (const float*)d_in[6];
    const int N = in_sizes[0] / 3;  // 16384

    // workspace layout (floats then ints)
    float* ws  = (float*)d_ws;
    float* sq  = ws;                                  // N
    float* pd  = sq + N;                              // N*NSEG*K_NN
    float* A   = pd + (size_t)N * NSEG * K_NN;        // N*128
    float* U   = A + (size_t)N * 128;                 // N*128
    float* h1  = U + (size_t)N * 128;                 // N*64
    float* h2  = h1 + (size_t)N * 64;                 // N*64
    int* pidx  = (int*)(h2 + (size_t)N * 64);         // N*NSEG*K_NN
    int* knn   = pidx + (size_t)N * NSEG * K_NN;      // N*K_NN
    float* out = (float*)d_out;

    const int qBlocks = N / 256;

    // ---- Layer 1 (C=3 -> F=64) ----
    sqnorm_kernel<3><<<qBlocks, 256, 0, stream>>>(x, sq, N);
    knn_partial_kernel<3><<<qBlocks * NSEG, 256, 0, stream>>>(x, sq, pd, pidx, N);
    knn_merge_kernel<<<qBlocks, 256, 0, stream>>>(pd, pidx, knn, N);
    proj_kernel<3, 64><<<(N * 64) / 256, 256, 0, stream>>>(x, W1, b1, A, U, N);
    agg_kernel<64><<<(N * 64) / 256, 256, 0, stream>>>(A, U, knn, h1, N);

    // ---- Layer 2 (C=64 -> F=64) ----
    sqnorm_kernel<64><<<qBlocks, 256, 0, stream>>>(h1, sq, N);
    knn_partial_kernel<64><<<qBlocks * NSEG, 256, 0, stream>>>(h1, sq, pd, pidx, N);
    knn_merge_kernel<<<qBlocks, 256, 0, stream>>>(pd, pidx, knn, N);
    proj_kernel<64, 64><<<(N * 64) / 256, 256, 0, stream>>>(h1, W2, b2, A, U, N);
    agg_kernel<64><<<(N * 64) / 256, 256, 0, stream>>>(A, U, knn, h2, N);

    // ---- Layer 3 (C=64 -> F=128) ----
    sqnorm_kernel<64><<<qBlocks, 256, 0, stream>>>(h2, sq, N);
    knn_partial_kernel<64><<<qBlocks * NSEG, 256, 0, stream>>>(h2, sq, pd, pidx, N);
    knn_merge_kernel<<<qBlocks, 256, 0, stream>>>(pd, pidx, knn, N);
    proj_kernel<64, 128><<<(N * 128) / 256, 256, 0, stream>>>(h2, W3, b3, A, U, N);
    agg_kernel<128><<<(N * 128) / 256, 256, 0, stream>>>(A, U, knn, out, N);
}